// Round 1
// 157.824 us; speedup vs baseline: 1.0201x; 1.0201x over previous
//
#include <hip/hip_runtime.h>

// CostTokenizer R7: occupancy 2 -> 3 blocks/CU.
//   rocprof R6: VALUBusy 27%, HBM 21%, occupancy 17% -> latency-bound, not
//   roofline-bound. LDS (50.2 KB, driven by the 2x[49][128] reduce slices)
//   capped residency at 2 blocks/CU; 672 blocks at 2/CU also left a
//   160-block low-occupancy tail.
//   Fix: split the 49-k reduce into two rounds (25 + 24) reusing ONE
//   2x[25][128] slice buffer -> LDS = max(6400, halo 5824) floats = 25.6 KB.
//   __launch_bounds__(256,3) -> 3 blocks/CU (12 waves), whole grid resident.
//   sA/sB bias-init deferred into round 0 so conv accumulators (96) never
//   coexist with all 98 corr accumulators (keeps combined regs under the
//   170/wave cap for 3 waves/SIMD).
//  - R6 rule kept: every loop indexing a register array is fully unrolled;
//    `unroll 1` only on loops touching LDS/global alone.
//  - 2-px vertical blocking: 56 ds_read_b128 feed 98 accumulators per chunk.
//  - halo row stride 26 float4 (104 floats = 8 mod 32): ty-groups at banks
//    0/8/16/24 -> 2-way bank aliasing = free.
//  - LDS union (reduce slices alias dead halos) + XCD column swizzle.
//
//  corr[k] = sum_c f1[c,h,w] * f2[c, (h-dy)%H, (w-dx)%W], k = (dy+3)*7 + (dx+3)
//  tok[t,b,d,h,w] = b[d] + (1/sqrt(C)) * sum_k corr[k] * w[k,d]

#define TD 192
#define HSTRIDE 26   // halo row stride in float4

template<int C, int H, int W, int TX, int TY>
__device__ __forceinline__ void level_tile(
    const float* __restrict__ lvl, const float* __restrict__ wm,
    const float* __restrict__ bias, float* __restrict__ out,
    int r, float scale, float* __restrict__ smem)
{
    const int HW = H * W;
    // XCD column-affinity: tiles of one column (pair,tX) are == mod 8 in bid
    const int xcd = r & 7, q = r >> 3;
    const int tY  = q % TY;
    const int col = (q / TY) * 8 + xcd;      // [0, 4*TX)
    const int pair = col / TX, tX = col % TX;

    const int t  = pair >> 1, bb = pair & 1;
    const float* f1 = lvl + (t * 2 + bb) * C * HW;
    const float* f2 = lvl + ((t + 1) * 2 + bb) * C * HW;

    const int tid  = threadIdx.x;
    const int lane = tid & 63;
    const int g    = tid >> 6;               // wave: channel group / d group
    const int tx   = lane & 15, tyy = lane >> 4;  // lane owns rows 2tyy, 2tyy+1
    const int x0   = tX * 16, y0 = tY * 8;
    const int x    = x0 + tx;
    const int y    = y0 + 2 * tyy;

    float4* h = (float4*)smem + g * (14 * HSTRIDE);  // wave halo: 14 rows

    // staging offsets for halo cells p in [0,308): row=p/22, col=p%22
    int goff[5], loff[5];
#pragma unroll
    for (int i = 0; i < 5; ++i) {
        int p = lane + i * 64;
        int rr = p / 22, cc = p - rr * 22;
        int gy = y0 - 3 + rr; if (gy < 0) gy += H; if (gy >= H) gy -= H;
        int gx = x0 - 3 + cc; if (gx < 0) gx += W; if (gx >= W) gx -= W;
        goff[i] = gy * W + gx;
        loff[i] = rr * HSTRIDE + cc;
    }

    float acc0[49], acc1[49];
#pragma unroll
    for (int k = 0; k < 49; ++k) { acc0[k] = 0.f; acc1[k] = 0.f; }

    // ---- phase 1: correlation, wave-synchronous (wave-private halo) ----
    const int NCH = C / 16;                  // 4-channel chunks per wave
    const float* f2c = f2 + g * (C / 4) * HW;
    const float* f1c = f1 + g * (C / 4) * HW + y * W + x;
#pragma unroll 1
    for (int cg = 0; cg < NCH; ++cg) {       // body touches LDS/global only via
#pragma unroll                               // fully-unrolled inner loops
        for (int i = 0; i < 5; ++i) {
            if (i < 4 || lane < 52) {
                const float* s = f2c + goff[i];
                float4 v; v.x = s[0]; v.y = s[HW]; v.z = s[2 * HW]; v.w = s[3 * HW];
                h[loff[i]] = v;
            }
        }
        float a00 = f1c[0], a01 = f1c[HW], a02 = f1c[2 * HW], a03 = f1c[3 * HW];
        float a10 = f1c[W], a11 = f1c[HW + W], a12 = f1c[2 * HW + W], a13 = f1c[3 * HW + W];
        f2c += 4 * HW; f1c += 4 * HW;
        // same-wave LDS RAW: compiler lgkmcnt waits cover it
#pragma unroll
        for (int b = 0; b < 7; ++b) {        // FULL unroll: indexes acc0/acc1
            const float4* hp = h + (2 * tyy) * HSTRIDE + (tx + 6 - b);
            // rolling window down the 8 rows: 2 float4 live per step
            float4 hi = hp[7 * HSTRIDE];
#pragma unroll
            for (int a = 0; a < 7; ++a) {
                float4 lo = hp[(6 - a) * HSTRIDE];
                float s0 = acc0[a * 7 + b], s1 = acc1[a * 7 + b];
                s0 = fmaf(a00, lo.x, s0); s0 = fmaf(a01, lo.y, s0);
                s0 = fmaf(a02, lo.z, s0); s0 = fmaf(a03, lo.w, s0);
                s1 = fmaf(a10, hi.x, s1); s1 = fmaf(a11, hi.y, s1);
                s1 = fmaf(a12, hi.z, s1); s1 = fmaf(a13, hi.w, s1);
                acc0[a * 7 + b] = s0; acc1[a * 7 + b] = s1;
                hi = lo;
            }
        }
    }

    // ---- phase 2+3: split-k reduce, two rounds over ONE 2x[25][128] buffer ----
    const int dbase = __builtin_amdgcn_readfirstlane(g * 48);
    float* s0p = smem;                       // [25][128]
    float* s1p = smem + 25 * 128;
    float sA[48], sB[48];                    // bias-init deferred to round 0

    __syncthreads();                         // all waves done with halos
#pragma unroll
    for (int rnd = 0; rnd < 2; ++rnd) {
        const int kbase = rnd * 25;
        const int kn = rnd ? 24 : 25;
        // cross-wave reduce for k in [kbase, kbase+kn)
        if (g >= 2) {
            float* dst = (g == 2) ? s0p : s1p;
#pragma unroll
            for (int k2 = 0; k2 < kn; ++k2) {   // FULL unroll: indexes acc0/acc1
                dst[k2 * 128 + lane]      = acc0[kbase + k2];
                dst[k2 * 128 + 64 + lane] = acc1[kbase + k2];
            }
        }
        __syncthreads();
        if (g < 2) {
            float* dst = (g == 0) ? s0p : s1p;
#pragma unroll
            for (int k2 = 0; k2 < kn; ++k2) {   // FULL unroll: indexes acc0/acc1
                dst[k2 * 128 + lane]      += acc0[kbase + k2];
                dst[k2 * 128 + 64 + lane] += acc1[kbase + k2];
            }
        }
        __syncthreads();
        // 49 -> 192 partial conv, wave g owns d in [48g, 48g+48), 2 px/lane
        if (rnd == 0) {
#pragma unroll
            for (int j = 0; j < 48; ++j) {      // FULL unroll: indexes sA/sB
                float bv = bias[dbase + j]; sA[j] = bv; sB[j] = bv;
            }
        }
#pragma unroll 1
        for (int k2 = 0; k2 < kn; ++k2) {    // rolled OK: k2 only indexes LDS/global
            float c0 = (s0p[k2 * 128 + lane]      + s1p[k2 * 128 + lane])      * scale;
            float c1 = (s0p[k2 * 128 + 64 + lane] + s1p[k2 * 128 + 64 + lane]) * scale;
            const float* wr = wm + (kbase + k2) * TD + dbase;   // wave-uniform -> s_load
#pragma unroll
            for (int j = 0; j < 48; ++j) {   // FULL unroll: indexes sA/sB
                float wv = wr[j];
                sA[j] = fmaf(wv, c0, sA[j]);
                sB[j] = fmaf(wv, c1, sB[j]);
            }
        }
        if (rnd == 0) __syncthreads();       // slices reread before round-1 writes
    }

    float* op = out + (pair * TD + dbase) * HW + y * W + x;
#pragma unroll
    for (int j = 0; j < 48; ++j) {           // FULL unroll: indexes sA/sB
        op[j * HW] = sA[j]; op[j * HW + W] = sB[j];
    }
}

__global__ __launch_bounds__(256, 3)
void cost_tokenizer(const float* __restrict__ l1, const float* __restrict__ l2,
                    const float* __restrict__ l3,
                    const float* __restrict__ w1, const float* __restrict__ b1,
                    const float* __restrict__ w2, const float* __restrict__ b2,
                    const float* __restrict__ w3, const float* __restrict__ b3,
                    float* __restrict__ out)
{
    __shared__ __align__(16) float smem[6400];  // max(2*25*128, 4*14*26*4) f = 25.6 KB
    int bid = blockIdx.x;
    // heavy levels first: L3 (12 chunks/wave), L2 (8), L1 (4)
    if (bid < 32) {
        level_tile<192, 32, 32, 2, 4>(l3, w3, b3, out + 15728640,
                                      bid, 0.072168783648703216f, smem);
    } else if (bid < 160) {
        level_tile<128, 64, 64, 4, 8>(l2, w2, b2, out + 12582912,
                                      bid - 32, 0.088388347648318447f, smem);
    } else {
        level_tile<64, 128, 128, 8, 16>(l1, w1, b1, out,
                                        bid - 160, 0.125f, smem);
    }
}

extern "C" void kernel_launch(void* const* d_in, const int* in_sizes, int n_in,
                              void* d_out, int out_size, void* d_ws, size_t ws_size,
                              hipStream_t stream)
{
    const float* l1 = (const float*)d_in[0];
    const float* l2 = (const float*)d_in[1];
    const float* l3 = (const float*)d_in[2];
    const float* w1 = (const float*)d_in[3];
    const float* b1 = (const float*)d_in[4];
    const float* w2 = (const float*)d_in[5];
    const float* b2 = (const float*)d_in[6];
    const float* w3 = (const float*)d_in[7];
    const float* b3 = (const float*)d_in[8];
    float* out = (float*)d_out;

    hipLaunchKernelGGL(cost_tokenizer, dim3(672), dim3(256), 0, stream,
                       l1, l2, l3, w1, b1, w2, b2, w3, b3, out);
}

// Round 2
// 156.026 us; speedup vs baseline: 1.0318x; 1.0115x over previous
//
#include <hip/hip_runtime.h>

// CostTokenizer R8: fix grid starvation -> 1344 blocks, 1 px/lane.
//   Post-mortem R7: splitting k to shrink LDS raised the per-CU block LIMIT
//   to 3 but the grid only offers 672/256 = 2.625 blocks/CU -> occupancy
//   stuck at ~21%, and the extra barrier round added ~18 us serial cost
//   (VALUBusy*dur conserved: 27*82 ~= 22*100). Kernel is latency-bound
//   (HBM floor 21 us, VALU floor 22 us, LDS floor 15 us vs 82-100 us);
//   the scarce resource is RESIDENT WAVES, capped by BLOCK COUNT.
//   Fix: halve the tile to 16x4 (1 px/lane) -> 1344 blocks (5.25/CU),
//   revert split-k (single 49-k reduce, slices 2x[49][64] = 25,088 B),
//   acc[49] per lane -> low VGPR -> __launch_bounds__(256,4) = 16 waves/CU.
//  - R6 rule kept: every loop indexing a register array is fully unrolled;
//    `unroll 1` only on loops touching LDS/global alone (scratch-spill trap).
//  - halo row stride 26 float4: read pattern (tx + 2*ty) mod 8 uniform over
//    bank-quads -> conflict-free-ish b128 reads (rows now consecutive).
//  - LDS union (reduce slices alias dead halos, 25.1 KB) + XCD column
//    swizzle (vertical halo-overlap neighbors share an XCD L2).
//
//  corr[k] = sum_c f1[c,h,w] * f2[c, (h-dy)%H, (w-dx)%W], k = (dy+3)*7 + (dx+3)
//  tok[t,b,d,h,w] = b[d] + (1/sqrt(C)) * sum_k corr[k] * w[k,d]

#define TD 192
#define HSTRIDE 26   // halo row stride in float4

template<int C, int H, int W, int TX, int TY>
__device__ __forceinline__ void level_tile(
    const float* __restrict__ lvl, const float* __restrict__ wm,
    const float* __restrict__ bias, float* __restrict__ out,
    int r, float scale, float* __restrict__ smem)
{
    const int HW = H * W;
    // XCD column-affinity: tiles of one column (pair,tX) are == mod 8 in bid
    const int xcd = r & 7, q = r >> 3;
    const int tY  = q % TY;
    const int col = (q / TY) * 8 + xcd;      // [0, 4*TX)
    const int pair = col / TX, tX = col % TX;

    const int t  = pair >> 1, bb = pair & 1;
    const float* f1 = lvl + (t * 2 + bb) * C * HW;
    const float* f2 = lvl + ((t + 1) * 2 + bb) * C * HW;

    const int tid  = threadIdx.x;
    const int lane = tid & 63;
    const int g    = tid >> 6;               // wave: channel group / d group
    const int tx   = lane & 15, ty = lane >> 4;   // lane owns row y0+ty
    const int x0   = tX * 16, y0 = tY * 4;
    const int x    = x0 + tx;
    const int y    = y0 + ty;

    float4* h = (float4*)smem + g * (10 * HSTRIDE);  // wave halo: 10 rows

    // staging offsets for halo cells p in [0,220): row=p/22, col=p%22
    int goff[4], loff[4];
#pragma unroll
    for (int i = 0; i < 4; ++i) {
        int p = lane + i * 64;
        int rr = p / 22, cc = p - rr * 22;
        int gy = y0 - 3 + rr; if (gy < 0) gy += H; if (gy >= H) gy -= H;
        int gx = x0 - 3 + cc; if (gx < 0) gx += W; if (gx >= W) gx -= W;
        goff[i] = gy * W + gx;
        loff[i] = rr * HSTRIDE + cc;
    }

    float acc[49];
#pragma unroll
    for (int k = 0; k < 49; ++k) acc[k] = 0.f;

    // ---- phase 1: correlation, wave-synchronous (wave-private halo) ----
    const int NCH = C / 16;                  // 4-channel chunks per wave
    const float* f2c = f2 + g * (C / 4) * HW;
    const float* f1c = f1 + g * (C / 4) * HW + y * W + x;
#pragma unroll 1
    for (int cg = 0; cg < NCH; ++cg) {       // body touches LDS/global only via
#pragma unroll                               // fully-unrolled inner loops
        for (int i = 0; i < 4; ++i) {
            if (i < 3 || lane < 28) {        // 220 cells
                const float* s = f2c + goff[i];
                float4 v; v.x = s[0]; v.y = s[HW]; v.z = s[2 * HW]; v.w = s[3 * HW];
                h[loff[i]] = v;
            }
        }
        float a0 = f1c[0], a1 = f1c[HW], a2 = f1c[2 * HW], a3 = f1c[3 * HW];
        f2c += 4 * HW; f1c += 4 * HW;
        // same-wave LDS RAW: compiler lgkmcnt waits cover it
#pragma unroll
        for (int b = 0; b < 7; ++b) {        // FULL unroll: indexes acc
            const float4* hp = h + ty * HSTRIDE + (tx + 6 - b);
#pragma unroll
            for (int a = 0; a < 7; ++a) {
                float4 lo = hp[(6 - a) * HSTRIDE];
                float s0 = acc[a * 7 + b];
                s0 = fmaf(a0, lo.x, s0); s0 = fmaf(a1, lo.y, s0);
                s0 = fmaf(a2, lo.z, s0); s0 = fmaf(a3, lo.w, s0);
                acc[a * 7 + b] = s0;
            }
        }
    }

    // ---- phase 2: cross-wave reduce; slices alias dead halo space ----
    __syncthreads();                         // all waves done with halos
    float* s0p = smem;                       // [49][64]
    float* s1p = smem + 49 * 64;
    if (g >= 2) {
        float* dst = (g == 2) ? s0p : s1p;
#pragma unroll
        for (int k = 0; k < 49; ++k)         // FULL unroll: indexes acc
            dst[k * 64 + lane] = acc[k];
    }
    __syncthreads();
    if (g < 2) {
        float* dst = (g == 0) ? s0p : s1p;
#pragma unroll
        for (int k = 0; k < 49; ++k)         // FULL unroll: indexes acc
            dst[k * 64 + lane] += acc[k];
    }
    __syncthreads();

    // ---- phase 3: 49 -> 192, wave g owns d in [48g, 48g+48), 1 px/lane ----
    const int dbase = __builtin_amdgcn_readfirstlane(g * 48);
    float sA[48];
#pragma unroll
    for (int j = 0; j < 48; ++j) sA[j] = bias[dbase + j];
#pragma unroll 1
    for (int k = 0; k < 49; ++k) {           // rolled OK: k only indexes LDS/global
        float c0 = (s0p[k * 64 + lane] + s1p[k * 64 + lane]) * scale;
        const float* wr = wm + k * TD + dbase;   // wave-uniform -> s_load
#pragma unroll
        for (int j = 0; j < 48; ++j)         // FULL unroll: indexes sA
            sA[j] = fmaf(wr[j], c0, sA[j]);
    }
    float* op = out + (pair * TD + dbase) * HW + y * W + x;
#pragma unroll
    for (int j = 0; j < 48; ++j)             // FULL unroll: indexes sA
        op[j * HW] = sA[j];
}

__global__ __launch_bounds__(256, 4)
void cost_tokenizer(const float* __restrict__ l1, const float* __restrict__ l2,
                    const float* __restrict__ l3,
                    const float* __restrict__ w1, const float* __restrict__ b1,
                    const float* __restrict__ w2, const float* __restrict__ b2,
                    const float* __restrict__ w3, const float* __restrict__ b3,
                    float* __restrict__ out)
{
    __shared__ __align__(16) float smem[6272];  // max(2*49*64, 4*10*26*4) f = 25.1 KB
    int bid = blockIdx.x;
    // heavy levels first: L3 (12 chunks/wave), L2 (8), L1 (4)
    if (bid < 64) {
        level_tile<192, 32, 32, 2, 8>(l3, w3, b3, out + 15728640,
                                      bid, 0.072168783648703216f, smem);
    } else if (bid < 320) {
        level_tile<128, 64, 64, 4, 16>(l2, w2, b2, out + 12582912,
                                       bid - 64, 0.088388347648318447f, smem);
    } else {
        level_tile<64, 128, 128, 8, 32>(l1, w1, b1, out,
                                        bid - 320, 0.125f, smem);
    }
}

extern "C" void kernel_launch(void* const* d_in, const int* in_sizes, int n_in,
                              void* d_out, int out_size, void* d_ws, size_t ws_size,
                              hipStream_t stream)
{
    const float* l1 = (const float*)d_in[0];
    const float* l2 = (const float*)d_in[1];
    const float* l3 = (const float*)d_in[2];
    const float* w1 = (const float*)d_in[3];
    const float* b1 = (const float*)d_in[4];
    const float* w2 = (const float*)d_in[5];
    const float* b2 = (const float*)d_in[6];
    const float* w3 = (const float*)d_in[7];
    const float* b3 = (const float*)d_in[8];
    float* out = (float*)d_out;

    hipLaunchKernelGGL(cost_tokenizer, dim3(1344), dim3(256), 0, stream,
                       l1, l2, l3, w1, b1, w2, b2, w3, b3, out);
}